// Round 1
// baseline (771.415 us; speedup 1.0000x reference)
//
#include <hip/hip_runtime.h>
#include <hip/hip_bf16.h>
#include <cstdint>

typedef __attribute__((ext_vector_type(8))) short short8;
typedef __attribute__((ext_vector_type(4))) float f32x4;

#define DEV static __device__ __forceinline__

DEV unsigned short f2bf(float f) {
  uint32_t u = __float_as_uint(f);
  uint32_t r = (u + 0x7FFFu + ((u >> 16) & 1u)) >> 16;
  return (unsigned short)r;
}

DEV unsigned short to_bf(float v) { return f2bf(v); }
DEV unsigned short to_bf(unsigned short v) { return v; }

// ---------------- elementwise f32 -> bf16 ----------------
__global__ __launch_bounds__(256) void convert_f32_bf16(const float* __restrict__ src,
                                                        unsigned short* __restrict__ dst,
                                                        long n) {
  long i = ((long)blockIdx.x * 256 + threadIdx.x) * 4;
  if (i >= n) return;
  float4 v = *(const float4*)&src[i];
  ushort4 o;
  o.x = f2bf(v.x); o.y = f2bf(v.y); o.z = f2bf(v.z); o.w = f2bf(v.w);
  *(ushort4*)&dst[i] = o;
}

// ---------------- transpose (+convert) -> bf16 ----------------
// dst[c][r] = bf16(src[r][c]); src is [R][C]
template<typename TIN>
__global__ __launch_bounds__(256) void transpose_to_bf16(const TIN* __restrict__ src,
                                                         unsigned short* __restrict__ dst,
                                                         int R, int C, long sS, long sD) {
  __shared__ unsigned short tile[32][33];
  int z = blockIdx.z;
  src += (long)z * sS;
  dst += (long)z * sD;
  int c0 = blockIdx.x * 32, r0 = blockIdx.y * 32;
  int tx = threadIdx.x & 31, ty = threadIdx.x >> 5;  // 32 x 8
  #pragma unroll
  for (int k = 0; k < 4; k++) {
    int rr = ty + k * 8;
    tile[rr][tx] = to_bf(src[(long)(r0 + rr) * C + c0 + tx]);
  }
  __syncthreads();
  #pragma unroll
  for (int k = 0; k < 4; k++) {
    int cc = ty + k * 8;
    dst[(long)(c0 + cc) * R + r0 + tx] = tile[tx][cc];
  }
}

// ---------------- gate = softmax(x @ Wg) ----------------
__global__ __launch_bounds__(256) void gate_kernel(const float* __restrict__ x,
                                                   const float* __restrict__ Wg,
                                                   float* __restrict__ gate, int Vdim) {
  int row = blockIdx.x * 4 + (threadIdx.x >> 6);
  int lane = threadIdx.x & 63;
  const float* xr = x + (long)row * Vdim;
  float a0 = 0.f, a1 = 0.f, a2 = 0.f;
  for (int c = lane; c < Vdim; c += 64) {
    float xv = xr[c];
    a0 += xv * Wg[c * 3 + 0];
    a1 += xv * Wg[c * 3 + 1];
    a2 += xv * Wg[c * 3 + 2];
  }
  #pragma unroll
  for (int off = 32; off; off >>= 1) {
    a0 += __shfl_xor(a0, off);
    a1 += __shfl_xor(a1, off);
    a2 += __shfl_xor(a2, off);
  }
  if (lane == 0) {
    float m = fmaxf(a0, fmaxf(a1, a2));
    float e0 = expf(a0 - m), e1 = expf(a1 - m), e2 = expf(a2 - m);
    float s = 1.f / (e0 + e1 + e2);
    gate[row * 3 + 0] = e0 * s;
    gate[row * 3 + 1] = e1 * s;
    gate[row * 3 + 2] = e2 * s;
  }
}

// ---------------- GEMM: C = A[M,K] * Bt[N,K]^T ----------------
enum { EPI_BF16 = 0, EPI_MASK_BF16 = 1, EPI_BLEND = 2, EPI_SCALE_F32 = 3 };
// TRI: 0 none, 1 scores (skip tiles fully below/at diagonal; mask epilogue), 2 kstart=m0

template<int EPI, int TRI>
__global__ __launch_bounds__(256) void gemm_bt(
    const unsigned short* __restrict__ A, const unsigned short* __restrict__ Bt,
    void* __restrict__ Cv, int M, int N, int K,
    long sA, long sB, long sC,
    const float* __restrict__ decay_logits, int scale_idx,
    const float* __restrict__ gate, const float* __restrict__ out_scale,
    int blend_init) {
  const int m0 = blockIdx.y * 128;
  const int n0 = blockIdx.x * 128;
  const int z = blockIdx.z;
  if (TRI == 1 && (n0 + 127) <= m0) return;  // fully masked score tile: never read downstream
  A += (long)z * sA;
  Bt += (long)z * sB;

  __shared__ unsigned short a_t[128][32];
  __shared__ unsigned short b_t[128][32];

  const int tid = threadIdx.x;
  const int wave = tid >> 6, lane = tid & 63;
  const int wm = wave >> 1, wn = wave & 1;
  const int lrow = lane & 15;
  const int g = lane >> 4;

  f32x4 acc[4][4];
  #pragma unroll
  for (int i = 0; i < 4; i++)
    #pragma unroll
    for (int j = 0; j < 4; j++) acc[i][j] = (f32x4){0.f, 0.f, 0.f, 0.f};

  const int srow = tid >> 2;              // 0..63
  const int scol = (tid & 3) * 8;         // 0,8,16,24
  const unsigned short* Arow0 = A + (long)(m0 + srow) * K;
  const unsigned short* Arow1 = A + (long)(m0 + srow + 64) * K;
  const unsigned short* Brow0 = Bt + (long)(n0 + srow) * K;
  const unsigned short* Brow1 = Bt + (long)(n0 + srow + 64) * K;

  const int kstart = (TRI == 2) ? m0 : 0;

  for (int k0 = kstart; k0 < K; k0 += 32) {
    *(short8*)&a_t[srow][scol]      = *(const short8*)&Arow0[k0 + scol];
    *(short8*)&a_t[srow + 64][scol] = *(const short8*)&Arow1[k0 + scol];
    *(short8*)&b_t[srow][scol]      = *(const short8*)&Brow0[k0 + scol];
    *(short8*)&b_t[srow + 64][scol] = *(const short8*)&Brow1[k0 + scol];
    __syncthreads();
    short8 af[4], bf[4];
    #pragma unroll
    for (int i = 0; i < 4; i++) af[i] = *(const short8*)&a_t[wm * 64 + i * 16 + lrow][g * 8];
    #pragma unroll
    for (int j = 0; j < 4; j++) bf[j] = *(const short8*)&b_t[wn * 64 + j * 16 + lrow][g * 8];
    #pragma unroll
    for (int i = 0; i < 4; i++)
      #pragma unroll
      for (int j = 0; j < 4; j++)
        acc[i][j] = __builtin_amdgcn_mfma_f32_16x16x32_bf16(af[i], bf[j], acc[i][j], 0, 0, 0);
    __syncthreads();
  }

  const int orow = m0 + wm * 64;
  const int ocol = n0 + wn * 64;

  if (EPI == EPI_BF16) {
    unsigned short* C = (unsigned short*)Cv + (long)z * sC;
    #pragma unroll
    for (int i = 0; i < 4; i++)
      #pragma unroll
      for (int j = 0; j < 4; j++)
        #pragma unroll
        for (int e = 0; e < 4; e++) {
          int r = orow + i * 16 + g * 4 + e;
          int c = ocol + j * 16 + lrow;
          C[(long)r * N + c] = f2bf(acc[i][j][e]);
        }
  } else if (EPI == EPI_MASK_BF16) {
    float dl = decay_logits[scale_idx];
    float decay = 1.f / (1.f + expf(-dl));
    float l2d = log2f(decay);
    unsigned short* C = (unsigned short*)Cv + (long)z * sC;
    #pragma unroll
    for (int i = 0; i < 4; i++)
      #pragma unroll
      for (int j = 0; j < 4; j++)
        #pragma unroll
        for (int e = 0; e < 4; e++) {
          int t = orow + i * 16 + g * 4 + e;
          int s = ocol + j * 16 + lrow;
          float w = (s > t) ? exp2f(l2d * (float)(s - t - 1)) : 0.f;
          C[(long)t * N + s] = f2bf(acc[i][j][e] * w);
        }
  } else if (EPI == EPI_BLEND) {
    float* C = (float*)Cv + (long)z * sC;
    #pragma unroll
    for (int i = 0; i < 4; i++) {
      #pragma unroll
      for (int e = 0; e < 4; e++) {
        int t = orow + i * 16 + g * 4 + e;
        float gv = gate[((long)z * M + t) * 3 + scale_idx];
        #pragma unroll
        for (int j = 0; j < 4; j++) {
          int d = ocol + j * 16 + lrow;
          long idx = (long)t * N + d;
          float val = gv * acc[i][j][e];
          C[idx] = blend_init ? val : (C[idx] + val);
        }
      }
    }
  } else {  // EPI_SCALE_F32
    float sc = *out_scale;
    float* C = (float*)Cv + (long)z * sC;
    #pragma unroll
    for (int i = 0; i < 4; i++)
      #pragma unroll
      for (int j = 0; j < 4; j++)
        #pragma unroll
        for (int e = 0; e < 4; e++) {
          int r = orow + i * 16 + g * 4 + e;
          int c = ocol + j * 16 + lrow;
          C[(long)r * N + c] = acc[i][j][e] * sc;
        }
  }
}

extern "C" void kernel_launch(void* const* d_in, const int* in_sizes, int n_in,
                              void* d_out, int out_size, void* d_ws, size_t ws_size,
                              hipStream_t stream) {
  const int B = 4, T = 2048, V = 2048, D = 512;
  const int M = B * T;  // 8192

  const float* x   = (const float*)d_in[0];
  const float* Wq  = (const float*)d_in[1];
  const float* Wk  = (const float*)d_in[2];
  const float* Wv  = (const float*)d_in[3];
  const float* Wo  = (const float*)d_in[4];
  const float* Wg  = (const float*)d_in[5];
  const float* dl  = (const float*)d_in[6];
  const float* osc = (const float*)d_in[7];

  char* p = (char*)d_ws;
  auto carve = [&](size_t bytes) -> void* {
    void* r = (void*)p;
    p += (bytes + 255) & ~(size_t)255;
    return r;
  };
  unsigned short* xb   = (unsigned short*)carve((size_t)M * V * 2);
  unsigned short* wqT  = (unsigned short*)carve((size_t)D * V * 2);
  unsigned short* wkT  = (unsigned short*)carve((size_t)3 * D * V * 2);
  unsigned short* wvT  = (unsigned short*)carve((size_t)3 * D * V * 2);
  unsigned short* woT  = (unsigned short*)carve((size_t)V * D * 2);
  unsigned short* qb   = (unsigned short*)carve((size_t)M * D * 2);
  unsigned short* kb   = (unsigned short*)carve((size_t)M * D * 2);
  unsigned short* vb   = (unsigned short*)carve((size_t)M * D * 2);
  unsigned short* vT   = (unsigned short*)carve((size_t)B * D * T * 2);
  unsigned short* sb   = (unsigned short*)carve((size_t)B * T * T * 2);
  float*          gate = (float*)carve((size_t)M * 3 * 4);
  float*          blnd = (float*)carve((size_t)M * D * 4);
  unsigned short* blb  = (unsigned short*)carve((size_t)M * D * 2);

  // 1. x -> bf16
  {
    long n = (long)M * V;
    convert_f32_bf16<<<dim3((unsigned)(n / 4 / 256)), dim3(256), 0, stream>>>(x, xb, n);
  }
  // 2. weight transposes (+bf16)
  transpose_to_bf16<float><<<dim3(D / 32, V / 32, 1), dim3(256), 0, stream>>>(Wq, wqT, V, D, 0, 0);
  transpose_to_bf16<float><<<dim3(D / 32, V / 32, 3), dim3(256), 0, stream>>>(Wk, wkT, V, D, (long)V * D, (long)D * V);
  transpose_to_bf16<float><<<dim3(D / 32, V / 32, 3), dim3(256), 0, stream>>>(Wv, wvT, V, D, (long)V * D, (long)D * V);
  transpose_to_bf16<float><<<dim3(V / 32, D / 32, 1), dim3(256), 0, stream>>>(Wo, woT, D, V, 0, 0);
  // 3. gate
  gate_kernel<<<dim3(M / 4), dim3(256), 0, stream>>>(x, Wg, gate, V);
  // 4. q = xb @ WqT^T
  gemm_bt<EPI_BF16, 0><<<dim3(D / 128, M / 128, 1), dim3(256), 0, stream>>>(
      xb, wqT, qb, M, D, V, 0, 0, 0, nullptr, 0, nullptr, nullptr, 0);
  // 5. per-scale
  for (int i = 0; i < 3; i++) {
    gemm_bt<EPI_BF16, 0><<<dim3(D / 128, M / 128, 1), dim3(256), 0, stream>>>(
        xb, wkT + (size_t)i * D * V, kb, M, D, V, 0, 0, 0, nullptr, 0, nullptr, nullptr, 0);
    gemm_bt<EPI_BF16, 0><<<dim3(D / 128, M / 128, 1), dim3(256), 0, stream>>>(
        xb, wvT + (size_t)i * D * V, vb, M, D, V, 0, 0, 0, nullptr, 0, nullptr, nullptr, 0);
    transpose_to_bf16<unsigned short><<<dim3(D / 32, T / 32, B), dim3(256), 0, stream>>>(
        vb, vT, T, D, (long)T * D, (long)D * T);
    // scores (masked, bf16): sb[b][t][s] = (q.k) * w(t,s)
    gemm_bt<EPI_MASK_BF16, 1><<<dim3(T / 128, T / 128, B), dim3(256), 0, stream>>>(
        qb, kb, sb, T, T, D, (long)T * D, (long)T * D, (long)T * T, dl, i, nullptr, nullptr, 0);
    // retrieved, gate-weighted accumulate into blended (fp32)
    gemm_bt<EPI_BLEND, 2><<<dim3(D / 128, T / 128, B), dim3(256), 0, stream>>>(
        sb, vT, blnd, T, D, T, (long)T * T, (long)D * T, (long)T * D, nullptr, i, gate, nullptr,
        (i == 0) ? 1 : 0);
  }
  // 6. blended -> bf16
  {
    long n = (long)M * D;
    convert_f32_bf16<<<dim3((unsigned)(n / 4 / 256)), dim3(256), 0, stream>>>(blnd, blb, n);
  }
  // 7. out = (blended @ Wo) * out_scale  (fp32 out)
  gemm_bt<EPI_SCALE_F32, 0><<<dim3(V / 128, M / 128, 1), dim3(256), 0, stream>>>(
      blb, woT, d_out, M, V, D, 0, 0, 0, nullptr, 0, nullptr, osc, 0);
}

// Round 2
// 573.228 us; speedup vs baseline: 1.3457x; 1.3457x over previous
//
#include <hip/hip_runtime.h>
#include <hip/hip_bf16.h>
#include <cstdint>

typedef __attribute__((ext_vector_type(8))) short short8;
typedef __attribute__((ext_vector_type(4))) float f32x4;

#define DEV static __device__ __forceinline__

DEV unsigned short f2bf(float f) {
  uint32_t u = __float_as_uint(f);
  uint32_t r = (u + 0x7FFFu + ((u >> 16) & 1u)) >> 16;
  return (unsigned short)r;
}

DEV unsigned short to_bf(float v) { return f2bf(v); }
DEV unsigned short to_bf(unsigned short v) { return v; }

// async global->LDS, 16B per lane (wave-uniform LDS base + lane*16 implicit)
DEV void async_copy16(const unsigned short* g, unsigned short* l) {
  __builtin_amdgcn_global_load_lds(
      (const __attribute__((address_space(1))) void*)g,
      (__attribute__((address_space(3))) void*)l, 16, 0, 0);
}

// bijective XCD swizzle (m204)
DEV int xcd_swizzle(int orig, int nwg) {
  int q = nwg >> 3, r = nwg & 7;
  int xcd = orig & 7, idx = orig >> 3;
  return (xcd < r ? xcd * (q + 1) : r * (q + 1) + (xcd - r) * q) + idx;
}

// ---------------- elementwise f32 -> bf16 ----------------
__global__ __launch_bounds__(256) void convert_f32_bf16(const float* __restrict__ src,
                                                        unsigned short* __restrict__ dst,
                                                        long n) {
  long i = ((long)blockIdx.x * 256 + threadIdx.x) * 4;
  if (i >= n) return;
  float4 v = *(const float4*)&src[i];
  ushort4 o;
  o.x = f2bf(v.x); o.y = f2bf(v.y); o.z = f2bf(v.z); o.w = f2bf(v.w);
  *(ushort4*)&dst[i] = o;
}

// ---------------- transpose (+convert) -> bf16 ----------------
// dst[c][r] = bf16(src[r][c]); src rows have stride ldS; dst rows stride R
template<typename TIN>
__global__ __launch_bounds__(256) void transpose_to_bf16(const TIN* __restrict__ src,
                                                         unsigned short* __restrict__ dst,
                                                         int R, int C, int ldS,
                                                         long sS, long sD) {
  __shared__ unsigned short tile[32][33];
  int z = blockIdx.z;
  src += (long)z * sS;
  dst += (long)z * sD;
  int c0 = blockIdx.x * 32, r0 = blockIdx.y * 32;
  int tx = threadIdx.x & 31, ty = threadIdx.x >> 5;  // 32 x 8
  #pragma unroll
  for (int k = 0; k < 4; k++) {
    int rr = ty + k * 8;
    tile[rr][tx] = to_bf(src[(long)(r0 + rr) * ldS + c0 + tx]);
  }
  __syncthreads();
  #pragma unroll
  for (int k = 0; k < 4; k++) {
    int cc = ty + k * 8;
    dst[(long)(c0 + cc) * R + r0 + tx] = tile[tx][cc];
  }
}

// ---------------- gate = softmax(x @ Wg) ----------------
__global__ __launch_bounds__(256) void gate_kernel(const float* __restrict__ x,
                                                   const float* __restrict__ Wg,
                                                   float* __restrict__ gate, int Vdim) {
  int row = blockIdx.x * 4 + (threadIdx.x >> 6);
  int lane = threadIdx.x & 63;
  const float* xr = x + (long)row * Vdim;
  float a0 = 0.f, a1 = 0.f, a2 = 0.f;
  for (int c = lane; c < Vdim; c += 64) {
    float xv = xr[c];
    a0 += xv * Wg[c * 3 + 0];
    a1 += xv * Wg[c * 3 + 1];
    a2 += xv * Wg[c * 3 + 2];
  }
  #pragma unroll
  for (int off = 32; off; off >>= 1) {
    a0 += __shfl_xor(a0, off);
    a1 += __shfl_xor(a1, off);
    a2 += __shfl_xor(a2, off);
  }
  if (lane == 0) {
    float m = fmaxf(a0, fmaxf(a1, a2));
    float e0 = expf(a0 - m), e1 = expf(a1 - m), e2 = expf(a2 - m);
    float s = 1.f / (e0 + e1 + e2);
    gate[row * 3 + 0] = e0 * s;
    gate[row * 3 + 1] = e1 * s;
    gate[row * 3 + 2] = e2 * s;
  }
}

// ---------------- GEMM: C = A[M,K](lda) * Bt[N,K](ldb)^T ----------------
enum { EPI_BF16 = 0, EPI_MASK_BF16 = 1, EPI_BLEND = 2, EPI_SCALE_F32 = 3 };
// TRI: 0 none, 1 scores (skip tiles fully below/at diagonal), 2 kstart=m0

template<int EPI, int TRI, int SWZ>
__global__ __launch_bounds__(256) void gemm_bt(
    const unsigned short* __restrict__ A, const unsigned short* __restrict__ Bt,
    void* __restrict__ Cv, int M, int N, int K,
    int lda, int ldb, int ldc,
    long sA, long sB, long sC,
    const float* __restrict__ decay_logits, int scale_idx,
    const float* __restrict__ gate, const float* __restrict__ out_scale,
    int blend_init) {
  int m0, n0;
  if (SWZ) {
    int nwg = gridDim.x * gridDim.y;
    int orig = blockIdx.y * gridDim.x + blockIdx.x;
    int wg = xcd_swizzle(orig, nwg);
    m0 = (wg / gridDim.x) * 128;
    n0 = (wg % gridDim.x) * 128;
  } else {
    m0 = blockIdx.y * 128;
    n0 = blockIdx.x * 128;
  }
  const int z = blockIdx.z;
  if (TRI == 1 && (n0 + 127) <= m0) return;  // fully masked score tile: never read downstream
  A += (long)z * sA;
  Bt += (long)z * sB;

  __shared__ unsigned short a_t[128][32];
  __shared__ unsigned short b_t[128][32];

  const int tid = threadIdx.x;
  const int wave = tid >> 6, lane = tid & 63;
  const int wm = wave >> 1, wn = wave & 1;
  const int lrow = lane & 15;
  const int g = lane >> 4;

  f32x4 acc[4][4];
  #pragma unroll
  for (int i = 0; i < 4; i++)
    #pragma unroll
    for (int j = 0; j < 4; j++) acc[i][j] = (f32x4){0.f, 0.f, 0.f, 0.f};

  // staging geometry: wave w stages rows [w*16, w*16+16) of each half
  const int srw = lane >> 2;            // 0..15
  const int scol = (lane & 3) * 8;      // element col within 32
  const unsigned short* Ag = A + (long)(m0 + wave * 16 + srw) * lda + scol;
  const unsigned short* Bg = Bt + (long)(n0 + wave * 16 + srw) * ldb + scol;
  unsigned short* aDst = &a_t[0][0] + wave * 512;
  unsigned short* bDst = &b_t[0][0] + wave * 512;

  const int kstart = (TRI == 2) ? m0 : 0;

  for (int k0 = kstart; k0 < K; k0 += 32) {
    async_copy16(Ag + k0, aDst);
    async_copy16(Ag + (long)64 * lda + k0, aDst + 2048);
    async_copy16(Bg + k0, bDst);
    async_copy16(Bg + (long)64 * ldb + k0, bDst + 2048);
    __syncthreads();
    short8 af[4], bf[4];
    #pragma unroll
    for (int i = 0; i < 4; i++) af[i] = *(const short8*)&a_t[wm * 64 + i * 16 + lrow][g * 8];
    #pragma unroll
    for (int j = 0; j < 4; j++) bf[j] = *(const short8*)&b_t[wn * 64 + j * 16 + lrow][g * 8];
    #pragma unroll
    for (int i = 0; i < 4; i++)
      #pragma unroll
      for (int j = 0; j < 4; j++)
        acc[i][j] = __builtin_amdgcn_mfma_f32_16x16x32_bf16(af[i], bf[j], acc[i][j], 0, 0, 0);
    __syncthreads();
  }

  const int orow = m0 + wm * 64;
  const int ocol = n0 + wn * 64;

  if (EPI == EPI_BF16) {
    unsigned short* C = (unsigned short*)Cv + (long)z * sC;
    #pragma unroll
    for (int i = 0; i < 4; i++)
      #pragma unroll
      for (int j = 0; j < 4; j++)
        #pragma unroll
        for (int e = 0; e < 4; e++) {
          int r = orow + i * 16 + g * 4 + e;
          int c = ocol + j * 16 + lrow;
          C[(long)r * ldc + c] = f2bf(acc[i][j][e]);
        }
  } else if (EPI == EPI_MASK_BF16) {
    float dl = decay_logits[scale_idx];
    float decay = 1.f / (1.f + expf(-dl));
    float l2d = log2f(decay);
    unsigned short* C = (unsigned short*)Cv + (long)z * sC;
    #pragma unroll
    for (int i = 0; i < 4; i++)
      #pragma unroll
      for (int j = 0; j < 4; j++)
        #pragma unroll
        for (int e = 0; e < 4; e++) {
          int t = orow + i * 16 + g * 4 + e;
          int s = ocol + j * 16 + lrow;
          float w = (s > t) ? exp2f(l2d * (float)(s - t - 1)) : 0.f;
          C[(long)t * ldc + s] = f2bf(acc[i][j][e] * w);
        }
  } else if (EPI == EPI_BLEND) {
    float* C = (float*)Cv + (long)z * sC;
    #pragma unroll
    for (int i = 0; i < 4; i++) {
      #pragma unroll
      for (int e = 0; e < 4; e++) {
        int t = orow + i * 16 + g * 4 + e;
        float gv = gate[((long)z * M + t) * 3 + scale_idx];
        #pragma unroll
        for (int j = 0; j < 4; j++) {
          int d = ocol + j * 16 + lrow;
          long idx = (long)t * ldc + d;
          float val = gv * acc[i][j][e];
          C[idx] = blend_init ? val : (C[idx] + val);
        }
      }
    }
  } else {  // EPI_SCALE_F32
    float sc = *out_scale;
    float* C = (float*)Cv + (long)z * sC;
    #pragma unroll
    for (int i = 0; i < 4; i++)
      #pragma unroll
      for (int j = 0; j < 4; j++)
        #pragma unroll
        for (int e = 0; e < 4; e++) {
          int r = orow + i * 16 + g * 4 + e;
          int c = ocol + j * 16 + lrow;
          C[(long)r * ldc + c] = acc[i][j][e] * sc;
        }
  }
}

extern "C" void kernel_launch(void* const* d_in, const int* in_sizes, int n_in,
                              void* d_out, int out_size, void* d_ws, size_t ws_size,
                              hipStream_t stream) {
  const int B = 4, T = 2048, V = 2048, D = 512;
  const int M = B * T;       // 8192
  const int NP = 7 * D;      // 3584 fused projection width

  const float* x   = (const float*)d_in[0];
  const float* Wq  = (const float*)d_in[1];
  const float* Wk  = (const float*)d_in[2];
  const float* Wv  = (const float*)d_in[3];
  const float* Wo  = (const float*)d_in[4];
  const float* Wg  = (const float*)d_in[5];
  const float* dl  = (const float*)d_in[6];
  const float* osc = (const float*)d_in[7];

  char* p = (char*)d_ws;
  auto carve = [&](size_t bytes) -> void* {
    void* r = (void*)p;
    p += (bytes + 255) & ~(size_t)255;
    return r;
  };
  unsigned short* xb   = (unsigned short*)carve((size_t)M * V * 2);
  // wall = [wqT | wkT(3) | wvT(3)] contiguous -> [3584, 2048]
  unsigned short* wall = (unsigned short*)carve((size_t)NP * V * 2);
  unsigned short* wqT  = wall;
  unsigned short* wkT  = wall + (size_t)D * V;
  unsigned short* wvT  = wall + (size_t)4 * D * V;
  unsigned short* woT  = (unsigned short*)carve((size_t)V * D * 2);
  unsigned short* qkv  = (unsigned short*)carve((size_t)M * NP * 2);
  unsigned short* vT   = (unsigned short*)carve((size_t)B * D * T * 2);
  unsigned short* sb   = (unsigned short*)carve((size_t)B * T * T * 2);
  float*          gate = (float*)carve((size_t)M * 3 * 4);
  float*          blnd = (float*)carve((size_t)M * D * 4);
  unsigned short* blb  = (unsigned short*)carve((size_t)M * D * 2);

  // 1. x -> bf16
  {
    long n = (long)M * V;
    convert_f32_bf16<<<dim3((unsigned)(n / 4 / 256)), dim3(256), 0, stream>>>(x, xb, n);
  }
  // 2. weight transposes (+bf16)
  transpose_to_bf16<float><<<dim3(D / 32, V / 32, 1), dim3(256), 0, stream>>>(Wq, wqT, V, D, D, 0, 0);
  transpose_to_bf16<float><<<dim3(D / 32, V / 32, 3), dim3(256), 0, stream>>>(Wk, wkT, V, D, D, (long)V * D, (long)D * V);
  transpose_to_bf16<float><<<dim3(D / 32, V / 32, 3), dim3(256), 0, stream>>>(Wv, wvT, V, D, D, (long)V * D, (long)D * V);
  transpose_to_bf16<float><<<dim3(V / 32, D / 32, 1), dim3(256), 0, stream>>>(Wo, woT, D, V, V, 0, 0);
  // 3. gate
  gate_kernel<<<dim3(M / 4), dim3(256), 0, stream>>>(x, Wg, gate, V);
  // 4. fused projections: qkv[M, 3584] = xb @ wall^T
  gemm_bt<EPI_BF16, 0, 1><<<dim3(NP / 128, M / 128, 1), dim3(256), 0, stream>>>(
      xb, wall, qkv, M, NP, V, V, V, NP, 0, 0, 0, nullptr, 0, nullptr, nullptr, 0);
  // 5. per-scale
  for (int i = 0; i < 3; i++) {
    // v_i^T : [B][D][T] from qkv cols [2048 + i*512, +512)
    transpose_to_bf16<unsigned short><<<dim3(D / 32, T / 32, B), dim3(256), 0, stream>>>(
        qkv + 2048 + i * 512, vT, T, D, NP, (long)T * NP, (long)D * T);
    // scores (masked, bf16): sb[b][t][s] = (q . k_i) * w(t,s)
    gemm_bt<EPI_MASK_BF16, 1, 0><<<dim3(T / 128, T / 128, B), dim3(256), 0, stream>>>(
        qkv, qkv + (1 + i) * 512, sb, T, T, D, NP, NP, T,
        (long)T * NP, (long)T * NP, (long)T * T, dl, i, nullptr, nullptr, 0);
    // retrieved, gate-weighted accumulate into blended (fp32)
    gemm_bt<EPI_BLEND, 2, 0><<<dim3(D / 128, T / 128, B), dim3(256), 0, stream>>>(
        sb, vT, blnd, T, D, T, T, T, D,
        (long)T * T, (long)D * T, (long)T * D, nullptr, i, gate, nullptr, (i == 0) ? 1 : 0);
  }
  // 6. blended -> bf16
  {
    long n = (long)M * D;
    convert_f32_bf16<<<dim3((unsigned)(n / 4 / 256)), dim3(256), 0, stream>>>(blnd, blb, n);
  }
  // 7. out = (blended @ Wo) * out_scale  (fp32 out)
  gemm_bt<EPI_SCALE_F32, 0, 1><<<dim3(V / 128, M / 128, 1), dim3(256), 0, stream>>>(
      blb, woT, d_out, M, V, D, D, D, V, 0, 0, 0, nullptr, 0, nullptr, osc, 0);
}

// Round 3
// 518.596 us; speedup vs baseline: 1.4875x; 1.1053x over previous
//
#include <hip/hip_runtime.h>
#include <hip/hip_bf16.h>
#include <cstdint>

typedef __attribute__((ext_vector_type(8))) short short8;
typedef __attribute__((ext_vector_type(4))) float f32x4;

#define DEV static __device__ __forceinline__

DEV unsigned short f2bf(float f) {
  uint32_t u = __float_as_uint(f);
  uint32_t r = (u + 0x7FFFu + ((u >> 16) & 1u)) >> 16;
  return (unsigned short)r;
}

DEV unsigned short to_bf(float v) { return f2bf(v); }
DEV unsigned short to_bf(unsigned short v) { return v; }

// async global->LDS, 16B per lane (wave-uniform LDS base + lane*16 implicit)
DEV void async_copy16(const unsigned short* g, unsigned short* l) {
  __builtin_amdgcn_global_load_lds(
      (const __attribute__((address_space(1))) void*)g,
      (__attribute__((address_space(3))) void*)l, 16, 0, 0);
}

// bijective XCD swizzle (m204)
DEV int xcd_swizzle(int orig, int nwg) {
  int q = nwg >> 3, r = nwg & 7;
  int xcd = orig & 7, idx = orig >> 3;
  return (xcd < r ? xcd * (q + 1) : r * (q + 1) + (xcd - r) * q) + idx;
}

// ---------------- elementwise f32 -> bf16 ----------------
__global__ __launch_bounds__(256) void convert_f32_bf16(const float* __restrict__ src,
                                                        unsigned short* __restrict__ dst,
                                                        long n) {
  long i = ((long)blockIdx.x * 256 + threadIdx.x) * 4;
  if (i >= n) return;
  float4 v = *(const float4*)&src[i];
  ushort4 o;
  o.x = f2bf(v.x); o.y = f2bf(v.y); o.z = f2bf(v.z); o.w = f2bf(v.w);
  *(ushort4*)&dst[i] = o;
}

// ---------------- transpose (+convert) -> bf16 ----------------
template<typename TIN>
__global__ __launch_bounds__(256) void transpose_to_bf16(const TIN* __restrict__ src,
                                                         unsigned short* __restrict__ dst,
                                                         int R, int C, int ldS,
                                                         long sS, long sD) {
  __shared__ unsigned short tile[32][33];
  int z = blockIdx.z;
  src += (long)z * sS;
  dst += (long)z * sD;
  int c0 = blockIdx.x * 32, r0 = blockIdx.y * 32;
  int tx = threadIdx.x & 31, ty = threadIdx.x >> 5;  // 32 x 8
  #pragma unroll
  for (int k = 0; k < 4; k++) {
    int rr = ty + k * 8;
    tile[rr][tx] = to_bf(src[(long)(r0 + rr) * ldS + c0 + tx]);
  }
  __syncthreads();
  #pragma unroll
  for (int k = 0; k < 4; k++) {
    int cc = ty + k * 8;
    dst[(long)(c0 + cc) * R + r0 + tx] = tile[tx][cc];
  }
}

// ---------------- gate = softmax(x @ Wg) ----------------
__global__ __launch_bounds__(256) void gate_kernel(const float* __restrict__ x,
                                                   const float* __restrict__ Wg,
                                                   float* __restrict__ gate, int Vdim) {
  int row = blockIdx.x * 4 + (threadIdx.x >> 6);
  int lane = threadIdx.x & 63;
  const float* xr = x + (long)row * Vdim;
  float a0 = 0.f, a1 = 0.f, a2 = 0.f;
  for (int c = lane; c < Vdim; c += 64) {
    float xv = xr[c];
    a0 += xv * Wg[c * 3 + 0];
    a1 += xv * Wg[c * 3 + 1];
    a2 += xv * Wg[c * 3 + 2];
  }
  #pragma unroll
  for (int off = 32; off; off >>= 1) {
    a0 += __shfl_xor(a0, off);
    a1 += __shfl_xor(a1, off);
    a2 += __shfl_xor(a2, off);
  }
  if (lane == 0) {
    float m = fmaxf(a0, fmaxf(a1, a2));
    float e0 = expf(a0 - m), e1 = expf(a1 - m), e2 = expf(a2 - m);
    float s = 1.f / (e0 + e1 + e2);
    gate[row * 3 + 0] = e0 * s;
    gate[row * 3 + 1] = e1 * s;
    gate[row * 3 + 2] = e2 * s;
  }
}

// ---------------- 128^2 GEMM (2-phase): C = A[M,K](lda) * Bt[N,K](ldb)^T ----------------
enum { EPI_BF16 = 0, EPI_MASK_BF16 = 1, EPI_BLEND = 2, EPI_SCALE_F32 = 3 };
// TRI: 0 none, 1 scores (skip tiles fully below/at diagonal), 2 kstart=m0

template<int EPI, int TRI, int SWZ>
__global__ __launch_bounds__(256) void gemm_bt(
    const unsigned short* __restrict__ A, const unsigned short* __restrict__ Bt,
    void* __restrict__ Cv, int M, int N, int K,
    int lda, int ldb, int ldc,
    long sA, long sB, long sC,
    const float* __restrict__ decay_logits, int scale_idx,
    const float* __restrict__ gate, const float* __restrict__ out_scale,
    int blend_init) {
  int m0, n0;
  if (SWZ) {
    int nwg = gridDim.x * gridDim.y;
    int orig = blockIdx.y * gridDim.x + blockIdx.x;
    int wg = xcd_swizzle(orig, nwg);
    m0 = (wg / gridDim.x) * 128;
    n0 = (wg % gridDim.x) * 128;
  } else {
    m0 = blockIdx.y * 128;
    n0 = blockIdx.x * 128;
  }
  const int z = blockIdx.z;
  if (TRI == 1 && (n0 + 127) <= m0) return;
  A += (long)z * sA;
  Bt += (long)z * sB;

  __shared__ unsigned short a_t[128][32];
  __shared__ unsigned short b_t[128][32];

  const int tid = threadIdx.x;
  const int wave = tid >> 6, lane = tid & 63;
  const int wm = wave >> 1, wn = wave & 1;
  const int lrow = lane & 15;
  const int g = lane >> 4;

  f32x4 acc[4][4];
  #pragma unroll
  for (int i = 0; i < 4; i++)
    #pragma unroll
    for (int j = 0; j < 4; j++) acc[i][j] = (f32x4){0.f, 0.f, 0.f, 0.f};

  const int srw = lane >> 2;
  const int scol = (lane & 3) * 8;
  const unsigned short* Ag = A + (long)(m0 + wave * 16 + srw) * lda + scol;
  const unsigned short* Bg = Bt + (long)(n0 + wave * 16 + srw) * ldb + scol;
  unsigned short* aDst = &a_t[0][0] + wave * 512;
  unsigned short* bDst = &b_t[0][0] + wave * 512;

  const int kstart = (TRI == 2) ? m0 : 0;

  for (int k0 = kstart; k0 < K; k0 += 32) {
    async_copy16(Ag + k0, aDst);
    async_copy16(Ag + (long)64 * lda + k0, aDst + 2048);
    async_copy16(Bg + k0, bDst);
    async_copy16(Bg + (long)64 * ldb + k0, bDst + 2048);
    __syncthreads();
    short8 af[4], bf[4];
    #pragma unroll
    for (int i = 0; i < 4; i++) af[i] = *(const short8*)&a_t[wm * 64 + i * 16 + lrow][g * 8];
    #pragma unroll
    for (int j = 0; j < 4; j++) bf[j] = *(const short8*)&b_t[wn * 64 + j * 16 + lrow][g * 8];
    #pragma unroll
    for (int i = 0; i < 4; i++)
      #pragma unroll
      for (int j = 0; j < 4; j++)
        acc[i][j] = __builtin_amdgcn_mfma_f32_16x16x32_bf16(af[i], bf[j], acc[i][j], 0, 0, 0);
    __syncthreads();
  }

  const int orow = m0 + wm * 64;
  const int ocol = n0 + wn * 64;

  if (EPI == EPI_BF16) {
    unsigned short* C = (unsigned short*)Cv + (long)z * sC;
    #pragma unroll
    for (int i = 0; i < 4; i++)
      #pragma unroll
      for (int j = 0; j < 4; j++)
        #pragma unroll
        for (int e = 0; e < 4; e++) {
          int r = orow + i * 16 + g * 4 + e;
          int c = ocol + j * 16 + lrow;
          C[(long)r * ldc + c] = f2bf(acc[i][j][e]);
        }
  } else if (EPI == EPI_MASK_BF16) {
    float dl = decay_logits[scale_idx];
    float decay = 1.f / (1.f + expf(-dl));
    float l2d = log2f(decay);
    unsigned short* C = (unsigned short*)Cv + (long)z * sC;
    #pragma unroll
    for (int i = 0; i < 4; i++)
      #pragma unroll
      for (int j = 0; j < 4; j++)
        #pragma unroll
        for (int e = 0; e < 4; e++) {
          int t = orow + i * 16 + g * 4 + e;
          int s = ocol + j * 16 + lrow;
          float w = (s > t) ? exp2f(l2d * (float)(s - t - 1)) : 0.f;
          C[(long)t * ldc + s] = f2bf(acc[i][j][e] * w);
        }
  } else if (EPI == EPI_BLEND) {
    float* C = (float*)Cv + (long)z * sC;
    #pragma unroll
    for (int i = 0; i < 4; i++) {
      #pragma unroll
      for (int e = 0; e < 4; e++) {
        int t = orow + i * 16 + g * 4 + e;
        float gv = gate[((long)z * M + t) * 3 + scale_idx];
        #pragma unroll
        for (int j = 0; j < 4; j++) {
          int d = ocol + j * 16 + lrow;
          long idx = (long)t * ldc + d;
          float val = gv * acc[i][j][e];
          C[idx] = blend_init ? val : (C[idx] + val);
        }
      }
    }
  } else {
    float sc = *out_scale;
    float* C = (float*)Cv + (long)z * sC;
    #pragma unroll
    for (int i = 0; i < 4; i++)
      #pragma unroll
      for (int j = 0; j < 4; j++)
        #pragma unroll
        for (int e = 0; e < 4; e++) {
          int r = orow + i * 16 + g * 4 + e;
          int c = ocol + j * 16 + lrow;
          C[(long)r * ldc + c] = acc[i][j][e] * sc;
        }
  }
}

// ---------------- 256^2 8-wave counted-vmcnt GEMM ----------------
// BM=BN=256, BK=64, 512 threads (2x4 waves), per-wave C = 128x64,
// LDS 128 KiB double-buffered, XOR-swizzle ((row&7)<<4) both-sides,
// vmcnt(8) counted wait (never 0 in main loop), setprio around MFMA.

DEV void stage_tile256(const unsigned short* A, const unsigned short* Bt,
                       int lda, int ldb, int m0, int n0, int k0,
                       int w, int rl, int colel, unsigned short* buf) {
  #pragma unroll
  for (int s = 0; s < 4; ++s)
    async_copy16(A + (long)(m0 + s * 64 + rl) * lda + k0 + colel,
                 buf + ((s * 8192 + w * 1024) >> 1));
  #pragma unroll
  for (int s = 0; s < 4; ++s)
    async_copy16(Bt + (long)(n0 + s * 64 + rl) * ldb + k0 + colel,
                 buf + 16384 + ((s * 8192 + w * 1024) >> 1));
}

template<int H, int JH>
DEV void compute_quad(const unsigned short* As, const unsigned short* Bs,
                      int wm, int wn, int lr, int g, f32x4 (&acc)[8][4]) {
  short8 af[4][2], bf[2][2];
  #pragma unroll
  for (int ii = 0; ii < 4; ++ii) {
    int row = wm * 128 + (H * 4 + ii) * 16 + lr;
    #pragma unroll
    for (int ks = 0; ks < 2; ++ks) {
      int cb = (ks * 64 + g * 16) ^ ((lr & 7) << 4);
      af[ii][ks] = *(const short8*)((const char*)As + row * 128 + cb);
    }
  }
  #pragma unroll
  for (int jj = 0; jj < 2; ++jj) {
    int row = wn * 64 + (JH * 2 + jj) * 16 + lr;
    #pragma unroll
    for (int ks = 0; ks < 2; ++ks) {
      int cb = (ks * 64 + g * 16) ^ ((lr & 7) << 4);
      bf[jj][ks] = *(const short8*)((const char*)Bs + row * 128 + cb);
    }
  }
  asm volatile("s_waitcnt lgkmcnt(0)" ::: "memory");
  __builtin_amdgcn_sched_barrier(0);
  __builtin_amdgcn_s_setprio(1);
  #pragma unroll
  for (int ii = 0; ii < 4; ++ii)
    #pragma unroll
    for (int jj = 0; jj < 2; ++jj)
      #pragma unroll
      for (int ks = 0; ks < 2; ++ks)
        acc[H * 4 + ii][JH * 2 + jj] = __builtin_amdgcn_mfma_f32_16x16x32_bf16(
            af[ii][ks], bf[jj][ks], acc[H * 4 + ii][JH * 2 + jj], 0, 0, 0);
  __builtin_amdgcn_s_setprio(0);
}

template<int EPI, int SWZ>
__global__ __launch_bounds__(512) void gemm256(
    const unsigned short* __restrict__ A, const unsigned short* __restrict__ Bt,
    void* __restrict__ Cv, int M, int N, int K, int lda, int ldb, int ldc,
    const float* __restrict__ out_scale) {
  __shared__ __align__(16) unsigned short lds[65536];  // 128 KiB: 2 bufs x (As 32K + Bs 32K)
  int m0, n0;
  {
    int gx = gridDim.x;
    int orig = blockIdx.y * gx + blockIdx.x;
    int wg = SWZ ? xcd_swizzle(orig, gx * gridDim.y) : orig;
    m0 = (wg / gx) * 256;
    n0 = (wg % gx) * 256;
  }
  const int tid = threadIdx.x;
  const int w = tid >> 6, lane = tid & 63;
  const int wm = w >> 2, wn = w & 3;
  const int lr = lane & 15, g = lane >> 4;
  const int rl = w * 8 + (lane >> 3);
  const int colel = ((lane & 7) ^ (lane >> 3)) << 3;  // pre-swizzled global col (elements)

  f32x4 acc[8][4];
  #pragma unroll
  for (int i = 0; i < 8; ++i)
    #pragma unroll
    for (int j = 0; j < 4; ++j) acc[i][j] = (f32x4){0.f, 0.f, 0.f, 0.f};

  const int nkt = K >> 6;
  stage_tile256(A, Bt, lda, ldb, m0, n0, 0, w, rl, colel, lds);
  int cur = 0;
  for (int t = 0; t < nkt - 1; ++t) {
    unsigned short* bufn = lds + ((cur ^ 1) << 15);
    stage_tile256(A, Bt, lda, ldb, m0, n0, (t + 1) << 6, w, rl, colel, bufn);
    asm volatile("s_waitcnt vmcnt(8)" ::: "memory");  // tile t resident; t+1's 8 stay in flight
    __builtin_amdgcn_s_barrier();
    __builtin_amdgcn_sched_barrier(0);
    const unsigned short* As = lds + (cur << 15);
    const unsigned short* Bs = As + 16384;
    compute_quad<0, 0>(As, Bs, wm, wn, lr, g, acc);
    compute_quad<0, 1>(As, Bs, wm, wn, lr, g, acc);
    compute_quad<1, 0>(As, Bs, wm, wn, lr, g, acc);
    compute_quad<1, 1>(As, Bs, wm, wn, lr, g, acc);
    __builtin_amdgcn_s_barrier();  // all waves done reading buf before next overwrite
    cur ^= 1;
  }
  asm volatile("s_waitcnt vmcnt(0)" ::: "memory");
  __builtin_amdgcn_s_barrier();
  __builtin_amdgcn_sched_barrier(0);
  {
    const unsigned short* As = lds + (cur << 15);
    const unsigned short* Bs = As + 16384;
    compute_quad<0, 0>(As, Bs, wm, wn, lr, g, acc);
    compute_quad<0, 1>(As, Bs, wm, wn, lr, g, acc);
    compute_quad<1, 0>(As, Bs, wm, wn, lr, g, acc);
    compute_quad<1, 1>(As, Bs, wm, wn, lr, g, acc);
  }

  const int orow = m0 + wm * 128;
  const int ocol = n0 + wn * 64;
  if (EPI == EPI_BF16) {
    unsigned short* C = (unsigned short*)Cv;
    #pragma unroll
    for (int i = 0; i < 8; ++i)
      #pragma unroll
      for (int j = 0; j < 4; ++j)
        #pragma unroll
        for (int e = 0; e < 4; ++e)
          C[(long)(orow + i * 16 + g * 4 + e) * ldc + ocol + j * 16 + lr] = f2bf(acc[i][j][e]);
  } else {  // EPI_SCALE_F32
    float sc = *out_scale;
    float* C = (float*)Cv;
    #pragma unroll
    for (int i = 0; i < 8; ++i)
      #pragma unroll
      for (int j = 0; j < 4; ++j)
        #pragma unroll
        for (int e = 0; e < 4; ++e)
          C[(long)(orow + i * 16 + g * 4 + e) * ldc + ocol + j * 16 + lr] = acc[i][j][e] * sc;
  }
}

extern "C" void kernel_launch(void* const* d_in, const int* in_sizes, int n_in,
                              void* d_out, int out_size, void* d_ws, size_t ws_size,
                              hipStream_t stream) {
  const int B = 4, T = 2048, V = 2048, D = 512;
  const int M = B * T;       // 8192
  const int NP = 7 * D;      // 3584 fused projection width

  const float* x   = (const float*)d_in[0];
  const float* Wq  = (const float*)d_in[1];
  const float* Wk  = (const float*)d_in[2];
  const float* Wv  = (const float*)d_in[3];
  const float* Wo  = (const float*)d_in[4];
  const float* Wg  = (const float*)d_in[5];
  const float* dl  = (const float*)d_in[6];
  const float* osc = (const float*)d_in[7];

  char* p = (char*)d_ws;
  auto carve = [&](size_t bytes) -> void* {
    void* r = (void*)p;
    p += (bytes + 255) & ~(size_t)255;
    return r;
  };
  unsigned short* xb   = (unsigned short*)carve((size_t)M * V * 2);
  unsigned short* wall = (unsigned short*)carve((size_t)NP * V * 2);
  unsigned short* wqT  = wall;
  unsigned short* wkT  = wall + (size_t)D * V;
  unsigned short* wvT  = wall + (size_t)4 * D * V;
  unsigned short* woT  = (unsigned short*)carve((size_t)V * D * 2);
  unsigned short* qkv  = (unsigned short*)carve((size_t)M * NP * 2);
  unsigned short* vT   = (unsigned short*)carve((size_t)B * D * T * 2);
  unsigned short* sb   = (unsigned short*)carve((size_t)B * T * T * 2);
  float*          gate = (float*)carve((size_t)M * 3 * 4);
  float*          blnd = (float*)carve((size_t)M * D * 4);
  unsigned short* blb  = (unsigned short*)carve((size_t)M * D * 2);

  // 1. x -> bf16
  {
    long n = (long)M * V;
    convert_f32_bf16<<<dim3((unsigned)(n / 4 / 256)), dim3(256), 0, stream>>>(x, xb, n);
  }
  // 2. weight transposes (+bf16)
  transpose_to_bf16<float><<<dim3(D / 32, V / 32, 1), dim3(256), 0, stream>>>(Wq, wqT, V, D, D, 0, 0);
  transpose_to_bf16<float><<<dim3(D / 32, V / 32, 3), dim3(256), 0, stream>>>(Wk, wkT, V, D, D, (long)V * D, (long)D * V);
  transpose_to_bf16<float><<<dim3(D / 32, V / 32, 3), dim3(256), 0, stream>>>(Wv, wvT, V, D, D, (long)V * D, (long)D * V);
  transpose_to_bf16<float><<<dim3(V / 32, D / 32, 1), dim3(256), 0, stream>>>(Wo, woT, D, V, V, 0, 0);
  // 3. gate
  gate_kernel<<<dim3(M / 4), dim3(256), 0, stream>>>(x, Wg, gate, V);
  // 4. fused projections: qkv[M, 3584] = xb @ wall^T   (256^2 counted-vmcnt kernel)
  gemm256<EPI_BF16, 1><<<dim3(NP / 256, M / 256, 1), dim3(512), 0, stream>>>(
      xb, wall, qkv, M, NP, V, V, V, NP, nullptr);
  // 5. per-scale
  for (int i = 0; i < 3; i++) {
    transpose_to_bf16<unsigned short><<<dim3(D / 32, T / 32, B), dim3(256), 0, stream>>>(
        qkv + 2048 + i * 512, vT, T, D, NP, (long)T * NP, (long)D * T);
    gemm_bt<EPI_MASK_BF16, 1, 0><<<dim3(T / 128, T / 128, B), dim3(256), 0, stream>>>(
        qkv, qkv + (1 + i) * 512, sb, T, T, D, NP, NP, T,
        (long)T * NP, (long)T * NP, (long)T * T, dl, i, nullptr, nullptr, 0);
    gemm_bt<EPI_BLEND, 2, 0><<<dim3(D / 128, T / 128, B), dim3(256), 0, stream>>>(
        sb, vT, blnd, T, D, T, T, T, D,
        (long)T * T, (long)D * T, (long)T * D, nullptr, i, gate, nullptr, (i == 0) ? 1 : 0);
  }
  // 6. blended -> bf16
  {
    long n = (long)M * D;
    convert_f32_bf16<<<dim3((unsigned)(n / 4 / 256)), dim3(256), 0, stream>>>(blnd, blb, n);
  }
  // 7. out = (blended @ Wo) * out_scale  (fp32 out, 256^2 kernel)
  gemm256<EPI_SCALE_F32, 1><<<dim3(V / 256, M / 256, 1), dim3(512), 0, stream>>>(
      blb, woT, d_out, M, V, D, D, D, V, osc);
}

// Round 5
// 393.501 us; speedup vs baseline: 1.9604x; 1.3179x over previous
//
#include <hip/hip_runtime.h>
#include <hip/hip_bf16.h>
#include <cstdint>

typedef __attribute__((ext_vector_type(8))) short short8;
typedef __attribute__((ext_vector_type(4))) float f32x4;

#define DEV static __device__ __forceinline__

DEV unsigned short f2bf(float f) {
  uint32_t u = __float_as_uint(f);
  uint32_t r = (u + 0x7FFFu + ((u >> 16) & 1u)) >> 16;
  return (unsigned short)r;
}

DEV unsigned short to_bf(float v) { return f2bf(v); }
DEV unsigned short to_bf(unsigned short v) { return v; }

// async global->LDS, 16B per lane (wave-uniform LDS base + lane*16 implicit)
DEV void async_copy16(const unsigned short* g, unsigned short* l) {
  __builtin_amdgcn_global_load_lds(
      (const __attribute__((address_space(1))) void*)g,
      (__attribute__((address_space(3))) void*)l, 16, 0, 0);
}

// bijective XCD swizzle (m204)
DEV int xcd_swizzle(int orig, int nwg) {
  int q = nwg >> 3, r = nwg & 7;
  int xcd = orig & 7, idx = orig >> 3;
  return (xcd < r ? xcd * (q + 1) : r * (q + 1) + (xcd - r) * q) + idx;
}

// ---------------- fused x->bf16 convert + gate softmax ----------------
__global__ __launch_bounds__(256) void convert_gate(
    const float* __restrict__ x, const float* __restrict__ Wg,
    unsigned short* __restrict__ xb, float* __restrict__ gate) {
  const int row = blockIdx.x;
  const float* xr = x + (long)row * 2048;
  unsigned short* xo = xb + (long)row * 2048;
  const int tid = threadIdx.x;
  float a0 = 0.f, a1 = 0.f, a2 = 0.f;
  #pragma unroll
  for (int u = 0; u < 2; ++u) {
    int c = u * 1024 + tid * 4;
    float4 v = *(const float4*)&xr[c];
    ushort4 o;
    o.x = f2bf(v.x); o.y = f2bf(v.y); o.z = f2bf(v.z); o.w = f2bf(v.w);
    *(ushort4*)&xo[c] = o;
    float vv[4] = {v.x, v.y, v.z, v.w};
    #pragma unroll
    for (int e = 0; e < 4; ++e) {
      a0 += vv[e] * Wg[(c + e) * 3 + 0];
      a1 += vv[e] * Wg[(c + e) * 3 + 1];
      a2 += vv[e] * Wg[(c + e) * 3 + 2];
    }
  }
  #pragma unroll
  for (int off = 32; off; off >>= 1) {
    a0 += __shfl_xor(a0, off);
    a1 += __shfl_xor(a1, off);
    a2 += __shfl_xor(a2, off);
  }
  __shared__ float red[3][4];
  const int w = tid >> 6, lane = tid & 63;
  if (lane == 0) { red[0][w] = a0; red[1][w] = a1; red[2][w] = a2; }
  __syncthreads();
  if (tid == 0) {
    float s0 = red[0][0] + red[0][1] + red[0][2] + red[0][3];
    float s1 = red[1][0] + red[1][1] + red[1][2] + red[1][3];
    float s2 = red[2][0] + red[2][1] + red[2][2] + red[2][3];
    float m = fmaxf(s0, fmaxf(s1, s2));
    float e0 = expf(s0 - m), e1 = expf(s1 - m), e2 = expf(s2 - m);
    float s = 1.f / (e0 + e1 + e2);
    gate[row * 3 + 0] = e0 * s;
    gate[row * 3 + 1] = e1 * s;
    gate[row * 3 + 2] = e2 * s;
  }
}

// ---------------- transpose (+convert) -> bf16 ----------------
template<typename TIN>
__global__ __launch_bounds__(256) void transpose_to_bf16(const TIN* __restrict__ src,
                                                         unsigned short* __restrict__ dst,
                                                         int R, int C, int ldS,
                                                         long sS, long sD) {
  __shared__ unsigned short tile[32][33];
  int z = blockIdx.z;
  src += (long)z * sS;
  dst += (long)z * sD;
  int c0 = blockIdx.x * 32, r0 = blockIdx.y * 32;
  int tx = threadIdx.x & 31, ty = threadIdx.x >> 5;  // 32 x 8
  #pragma unroll
  for (int k = 0; k < 4; k++) {
    int rr = ty + k * 8;
    tile[rr][tx] = to_bf(src[(long)(r0 + rr) * ldS + c0 + tx]);
  }
  __syncthreads();
  #pragma unroll
  for (int k = 0; k < 4; k++) {
    int cc = ty + k * 8;
    dst[(long)(c0 + cc) * R + r0 + tx] = tile[tx][cc];
  }
}

// ---------------- 128^2 GEMM (2-phase): C = A[M,K](lda) * Bt[N,K](ldb)^T ----------------
enum { EPI_BF16 = 0, EPI_MASK_BF16 = 1, EPI_BLEND = 2, EPI_SCALE_F32 = 3, EPI_BLEND_F = 4 };
// TRI: 0 none, 1 scores (triangle + decay-band tile skip), 2 retrieved (kstart=m0, kend=band)

template<int EPI, int TRI, int SWZ>
__global__ __launch_bounds__(256) void gemm_bt(
    const unsigned short* __restrict__ A, const unsigned short* __restrict__ Bt,
    void* __restrict__ Cv, void* __restrict__ Cv2, int M, int N, int K,
    int lda, int ldb, int ldc,
    long sA, long sB, long sC,
    const float* __restrict__ decay_logits, int scale_idx,
    const float* __restrict__ gate, const float* __restrict__ out_scale,
    int blend_init) {
  int m0, n0;
  if (SWZ) {
    int nwg = gridDim.x * gridDim.y;
    int orig = blockIdx.y * gridDim.x + blockIdx.x;
    int wg = xcd_swizzle(orig, nwg);
    m0 = (wg / gridDim.x) * 128;
    n0 = (wg % gridDim.x) * 128;
  } else {
    m0 = blockIdx.y * 128;
    n0 = blockIdx.x * 128;
  }
  const int z = blockIdx.z;
  if (TRI == 1 && (n0 + 127) <= m0) return;

  // decay band: terms with w < 2^-24 are numerically irrelevant.
  // CLAMP AGAINST THE s-EXTENT: scores (TRI=1) band lives along N; retrieved
  // (TRI=2) band lives along K. (Round-4 bug: clamped scores band to K=D.)
  float l2d_s = 0.f;
  int bandt = K;
  if (TRI == 1 || TRI == 2) {
    const int lim = (TRI == 1) ? N : K;
    float dlv = decay_logits[scale_idx];
    float decay = 1.f / (1.f + expf(-dlv));
    l2d_s = log2f(decay);
    float bf_ = 24.0f / fmaxf(-l2d_s, 1e-9f) + 129.0f;
    bandt = (bf_ >= (float)lim) ? lim : ((int)ceilf(bf_ / 128.0f)) * 128;
    if (bandt > lim) bandt = lim;
  }
  if (TRI == 1 && n0 >= m0 + bandt) return;

  A += (long)z * sA;
  Bt += (long)z * sB;

  __shared__ unsigned short a_t[128][32];
  __shared__ unsigned short b_t[128][32];

  const int tid = threadIdx.x;
  const int wave = tid >> 6, lane = tid & 63;
  const int wm = wave >> 1, wn = wave & 1;
  const int lrow = lane & 15;
  const int g = lane >> 4;

  f32x4 acc[4][4];
  #pragma unroll
  for (int i = 0; i < 4; i++)
    #pragma unroll
    for (int j = 0; j < 4; j++) acc[i][j] = (f32x4){0.f, 0.f, 0.f, 0.f};

  const int srw = lane >> 2;
  const int scol = (lane & 3) * 8;
  const unsigned short* Ag = A + (long)(m0 + wave * 16 + srw) * lda + scol;
  const unsigned short* Bg = Bt + (long)(n0 + wave * 16 + srw) * ldb + scol;
  unsigned short* aDst = &a_t[0][0] + wave * 512;
  unsigned short* bDst = &b_t[0][0] + wave * 512;

  const int kstart = (TRI == 2) ? m0 : 0;
  const int kend = (TRI == 2) ? min(K, m0 + bandt) : K;

  for (int k0 = kstart; k0 < kend; k0 += 32) {
    async_copy16(Ag + k0, aDst);
    async_copy16(Ag + (long)64 * lda + k0, aDst + 2048);
    async_copy16(Bg + k0, bDst);
    async_copy16(Bg + (long)64 * ldb + k0, bDst + 2048);
    __syncthreads();
    short8 af[4], bf[4];
    #pragma unroll
    for (int i = 0; i < 4; i++) af[i] = *(const short8*)&a_t[wm * 64 + i * 16 + lrow][g * 8];
    #pragma unroll
    for (int j = 0; j < 4; j++) bf[j] = *(const short8*)&b_t[wn * 64 + j * 16 + lrow][g * 8];
    #pragma unroll
    for (int i = 0; i < 4; i++)
      #pragma unroll
      for (int j = 0; j < 4; j++)
        acc[i][j] = __builtin_amdgcn_mfma_f32_16x16x32_bf16(af[i], bf[j], acc[i][j], 0, 0, 0);
    __syncthreads();
  }

  const int orow = m0 + wm * 64;
  const int ocol = n0 + wn * 64;

  if (EPI == EPI_BF16) {
    unsigned short* C = (unsigned short*)Cv + (long)z * sC;
    #pragma unroll
    for (int i = 0; i < 4; i++)
      #pragma unroll
      for (int j = 0; j < 4; j++)
        #pragma unroll
        for (int e = 0; e < 4; e++) {
          int r = orow + i * 16 + g * 4 + e;
          int c = ocol + j * 16 + lrow;
          C[(long)r * ldc + c] = f2bf(acc[i][j][e]);
        }
  } else if (EPI == EPI_MASK_BF16) {
    unsigned short* C = (unsigned short*)Cv + (long)z * sC;
    #pragma unroll
    for (int i = 0; i < 4; i++)
      #pragma unroll
      for (int j = 0; j < 4; j++)
        #pragma unroll
        for (int e = 0; e < 4; e++) {
          int t = orow + i * 16 + g * 4 + e;
          int s = ocol + j * 16 + lrow;
          float w = (s > t) ? exp2f(l2d_s * (float)(s - t - 1)) : 0.f;
          C[(long)t * ldc + s] = f2bf(acc[i][j][e] * w);
        }
  } else if (EPI == EPI_BLEND || EPI == EPI_BLEND_F) {
    float* C = (float*)Cv + (long)z * sC;
    unsigned short* C2 = (unsigned short*)Cv2 + (long)z * sC;
    #pragma unroll
    for (int i = 0; i < 4; i++) {
      #pragma unroll
      for (int e = 0; e < 4; e++) {
        int t = orow + i * 16 + g * 4 + e;
        float gv = gate[((long)z * M + t) * 3 + scale_idx];
        #pragma unroll
        for (int j = 0; j < 4; j++) {
          int d = ocol + j * 16 + lrow;
          long idx = (long)t * ldc + d;
          float val = gv * acc[i][j][e];
          if (EPI == EPI_BLEND) {
            C[idx] = blend_init ? val : (C[idx] + val);
          } else {
            C2[idx] = f2bf(C[idx] + val);  // final scale: accumulate + cast to bf16
          }
        }
      }
    }
  } else {
    float sc = *out_scale;
    float* C = (float*)Cv + (long)z * sC;
    #pragma unroll
    for (int i = 0; i < 4; i++)
      #pragma unroll
      for (int j = 0; j < 4; j++)
        #pragma unroll
        for (int e = 0; e < 4; e++) {
          int r = orow + i * 16 + g * 4 + e;
          int c = ocol + j * 16 + lrow;
          C[(long)r * ldc + c] = acc[i][j][e] * sc;
        }
  }
}

// ---------------- 256^2 8-wave counted-vmcnt GEMM ----------------
DEV void stage_tile256(const unsigned short* A, const unsigned short* Bt,
                       int lda, int ldb, int m0, int n0, int k0,
                       int w, int rl, int colel, unsigned short* buf) {
  #pragma unroll
  for (int s = 0; s < 4; ++s)
    async_copy16(A + (long)(m0 + s * 64 + rl) * lda + k0 + colel,
                 buf + ((s * 8192 + w * 1024) >> 1));
  #pragma unroll
  for (int s = 0; s < 4; ++s)
    async_copy16(Bt + (long)(n0 + s * 64 + rl) * ldb + k0 + colel,
                 buf + 16384 + ((s * 8192 + w * 1024) >> 1));
}

DEV void compute_tile256(const unsigned short* As, const unsigned short* Bs,
                         int wm, int wn, int lr, int g, f32x4 (&acc)[8][4]) {
  // each fragment read exactly once: 12 ds_read_b128 per ks-half, 24 total
  #pragma unroll
  for (int ks = 0; ks < 2; ++ks) {
    const int cb = (ks * 64 + g * 16) ^ ((lr & 7) << 4);
    short8 af[8], bf[4];
    #pragma unroll
    for (int ii = 0; ii < 8; ++ii)
      af[ii] = *(const short8*)((const char*)As + (wm * 128 + ii * 16 + lr) * 128 + cb);
    #pragma unroll
    for (int jj = 0; jj < 4; ++jj)
      bf[jj] = *(const short8*)((const char*)Bs + (wn * 64 + jj * 16 + lr) * 128 + cb);
    __builtin_amdgcn_s_setprio(1);
    #pragma unroll
    for (int ii = 0; ii < 8; ++ii)
      #pragma unroll
      for (int jj = 0; jj < 4; ++jj)
        acc[ii][jj] = __builtin_amdgcn_mfma_f32_16x16x32_bf16(af[ii], bf[jj], acc[ii][jj], 0, 0, 0);
    __builtin_amdgcn_s_setprio(0);
  }
}

template<int EPI, int SWZ>
__global__ __launch_bounds__(512) void gemm256(
    const unsigned short* __restrict__ A, const unsigned short* __restrict__ Bt,
    void* __restrict__ Cv, int M, int N, int K, int lda, int ldb, int ldc,
    const float* __restrict__ out_scale) {
  __shared__ __align__(16) unsigned short lds[65536];  // 2 bufs x (As 32K + Bs 32K)
  int m0, n0;
  {
    int gx = gridDim.x;
    int orig = blockIdx.y * gx + blockIdx.x;
    int wg = SWZ ? xcd_swizzle(orig, gx * gridDim.y) : orig;
    m0 = (wg / gx) * 256;
    n0 = (wg % gx) * 256;
  }
  const int tid = threadIdx.x;
  const int w = tid >> 6, lane = tid & 63;
  const int wm = w >> 2, wn = w & 3;
  const int lr = lane & 15, g = lane >> 4;
  const int rl = w * 8 + (lane >> 3);
  const int colel = ((lane & 7) ^ (lane >> 3)) << 3;  // pre-swizzled global col (elements)

  f32x4 acc[8][4];
  #pragma unroll
  for (int i = 0; i < 8; ++i)
    #pragma unroll
    for (int j = 0; j < 4; ++j) acc[i][j] = (f32x4){0.f, 0.f, 0.f, 0.f};

  const int nkt = K >> 6;
  stage_tile256(A, Bt, lda, ldb, m0, n0, 0, w, rl, colel, lds);
  int cur = 0;
  for (int t = 0; t < nkt - 1; ++t) {
    unsigned short* bufn = lds + ((cur ^ 1) << 15);
    stage_tile256(A, Bt, lda, ldb, m0, n0, (t + 1) << 6, w, rl, colel, bufn);
    asm volatile("s_waitcnt vmcnt(8)" ::: "memory");  // tile t resident; t+1's 8 in flight
    __builtin_amdgcn_s_barrier();
    __builtin_amdgcn_sched_barrier(0);
    const unsigned short* As = lds + (cur << 15);
    compute_tile256(As, As + 16384, wm, wn, lr, g, acc);
    __builtin_amdgcn_s_barrier();  // all waves done reading buf before overwrite
    cur ^= 1;
  }
  asm volatile("s_waitcnt vmcnt(0)" ::: "memory");
  __builtin_amdgcn_s_barrier();
  __builtin_amdgcn_sched_barrier(0);
  {
    const unsigned short* As = lds + (cur << 15);
    compute_tile256(As, As + 16384, wm, wn, lr, g, acc);
  }

  const int orow = m0 + wm * 128;
  const int ocol = n0 + wn * 64;
  if (EPI == EPI_BF16) {
    unsigned short* C = (unsigned short*)Cv;
    #pragma unroll
    for (int i = 0; i < 8; ++i)
      #pragma unroll
      for (int j = 0; j < 4; ++j)
        #pragma unroll
        for (int e = 0; e < 4; ++e)
          C[(long)(orow + i * 16 + g * 4 + e) * ldc + ocol + j * 16 + lr] = f2bf(acc[i][j][e]);
  } else {  // EPI_SCALE_F32
    float sc = *out_scale;
    float* C = (float*)Cv;
    #pragma unroll
    for (int i = 0; i < 8; ++i)
      #pragma unroll
      for (int j = 0; j < 4; ++j)
        #pragma unroll
        for (int e = 0; e < 4; ++e)
          C[(long)(orow + i * 16 + g * 4 + e) * ldc + ocol + j * 16 + lr] = acc[i][j][e] * sc;
  }
}

extern "C" void kernel_launch(void* const* d_in, const int* in_sizes, int n_in,
                              void* d_out, int out_size, void* d_ws, size_t ws_size,
                              hipStream_t stream) {
  const int B = 4, T = 2048, V = 2048, D = 512;
  const int M = B * T;       // 8192
  const int NP = 7 * D;      // 3584 fused projection width

  const float* x   = (const float*)d_in[0];
  const float* Wq  = (const float*)d_in[1];
  const float* Wk  = (const float*)d_in[2];
  const float* Wv  = (const float*)d_in[3];
  const float* Wo  = (const float*)d_in[4];
  const float* Wg  = (const float*)d_in[5];
  const float* dl  = (const float*)d_in[6];
  const float* osc = (const float*)d_in[7];

  char* p = (char*)d_ws;
  auto carve = [&](size_t bytes) -> void* {
    void* r = (void*)p;
    p += (bytes + 255) & ~(size_t)255;
    return r;
  };
  unsigned short* xb   = (unsigned short*)carve((size_t)M * V * 2);
  unsigned short* wall = (unsigned short*)carve((size_t)NP * V * 2);
  unsigned short* wqT  = wall;
  unsigned short* wkT  = wall + (size_t)D * V;
  unsigned short* wvT  = wall + (size_t)4 * D * V;
  unsigned short* woT  = (unsigned short*)carve((size_t)V * D * 2);
  unsigned short* qkv  = (unsigned short*)carve((size_t)M * NP * 2);
  unsigned short* vT   = (unsigned short*)carve((size_t)B * D * T * 2);
  unsigned short* sb   = (unsigned short*)carve((size_t)B * T * T * 2);
  float*          gate = (float*)carve((size_t)M * 3 * 4);
  float*          blnd = (float*)carve((size_t)M * D * 4);
  unsigned short* blb  = (unsigned short*)carve((size_t)M * D * 2);

  // 1. fused x->bf16 + gate softmax
  convert_gate<<<dim3(M), dim3(256), 0, stream>>>(x, Wg, xb, gate);
  // 2. weight transposes (+bf16)
  transpose_to_bf16<float><<<dim3(D / 32, V / 32, 1), dim3(256), 0, stream>>>(Wq, wqT, V, D, D, 0, 0);
  transpose_to_bf16<float><<<dim3(D / 32, V / 32, 3), dim3(256), 0, stream>>>(Wk, wkT, V, D, D, (long)V * D, (long)D * V);
  transpose_to_bf16<float><<<dim3(D / 32, V / 32, 3), dim3(256), 0, stream>>>(Wv, wvT, V, D, D, (long)V * D, (long)D * V);
  transpose_to_bf16<float><<<dim3(V / 32, D / 32, 1), dim3(256), 0, stream>>>(Wo, woT, D, V, V, 0, 0);
  // 3. fused projections: qkv[M, 3584] = xb @ wall^T
  gemm256<EPI_BF16, 1><<<dim3(NP / 256, M / 256, 1), dim3(512), 0, stream>>>(
      xb, wall, qkv, M, NP, V, V, V, NP, nullptr);
  // 4. per-scale
  for (int i = 0; i < 3; i++) {
    transpose_to_bf16<unsigned short><<<dim3(D / 32, T / 32, B), dim3(256), 0, stream>>>(
        qkv + 2048 + i * 512, vT, T, D, NP, (long)T * NP, (long)D * T);
    gemm_bt<EPI_MASK_BF16, 1, 0><<<dim3(T / 128, T / 128, B), dim3(256), 0, stream>>>(
        qkv, qkv + (1 + i) * 512, sb, nullptr, T, T, D, NP, NP, T,
        (long)T * NP, (long)T * NP, (long)T * T, dl, i, nullptr, nullptr, 0);
    if (i < 2)
      gemm_bt<EPI_BLEND, 2, 0><<<dim3(D / 128, T / 128, B), dim3(256), 0, stream>>>(
          sb, vT, blnd, nullptr, T, D, T, T, T, D,
          (long)T * T, (long)D * T, (long)T * D, dl, i, gate, nullptr, (i == 0) ? 1 : 0);
    else
      gemm_bt<EPI_BLEND_F, 2, 0><<<dim3(D / 128, T / 128, B), dim3(256), 0, stream>>>(
          sb, vT, blnd, blb, T, D, T, T, T, D,
          (long)T * T, (long)D * T, (long)T * D, dl, i, gate, nullptr, 0);
  }
  // 5. out = (blended @ Wo) * out_scale  (fp32 out)
  gemm256<EPI_SCALE_F32, 1><<<dim3(V / 256, M / 256, 1), dim3(512), 0, stream>>>(
      blb, woT, d_out, M, V, D, D, D, V, osc);
}

// Round 6
// 384.632 us; speedup vs baseline: 2.0056x; 1.0231x over previous
//
#include <hip/hip_runtime.h>
#include <hip/hip_bf16.h>
#include <cstdint>

typedef __attribute__((ext_vector_type(8))) short short8;
typedef __attribute__((ext_vector_type(4))) float f32x4;

#define DEV static __device__ __forceinline__

DEV unsigned short f2bf(float f) {
  uint32_t u = __float_as_uint(f);
  uint32_t r = (u + 0x7FFFu + ((u >> 16) & 1u)) >> 16;
  return (unsigned short)r;
}

DEV unsigned short to_bf(float v) { return f2bf(v); }
DEV unsigned short to_bf(unsigned short v) { return v; }

// async global->LDS, 16B per lane (wave-uniform LDS base + lane*16 implicit)
DEV void async_copy16(const unsigned short* g, unsigned short* l) {
  __builtin_amdgcn_global_load_lds(
      (const __attribute__((address_space(1))) void*)g,
      (__attribute__((address_space(3))) void*)l, 16, 0, 0);
}

// bijective XCD swizzle (m204)
DEV int xcd_swizzle(int orig, int nwg) {
  int q = nwg >> 3, r = nwg & 7;
  int xcd = orig & 7, idx = orig >> 3;
  return (xcd < r ? xcd * (q + 1) : r * (q + 1) + (xcd - r) * q) + idx;
}

// ---------------- fused x->bf16 convert + gate softmax ----------------
__global__ __launch_bounds__(256) void convert_gate(
    const float* __restrict__ x, const float* __restrict__ Wg,
    unsigned short* __restrict__ xb, float* __restrict__ gate) {
  const int row = blockIdx.x;
  const float* xr = x + (long)row * 2048;
  unsigned short* xo = xb + (long)row * 2048;
  const int tid = threadIdx.x;
  float a0 = 0.f, a1 = 0.f, a2 = 0.f;
  #pragma unroll
  for (int u = 0; u < 2; ++u) {
    int c = u * 1024 + tid * 4;
    float4 v = *(const float4*)&xr[c];
    ushort4 o;
    o.x = f2bf(v.x); o.y = f2bf(v.y); o.z = f2bf(v.z); o.w = f2bf(v.w);
    *(ushort4*)&xo[c] = o;
    float vv[4] = {v.x, v.y, v.z, v.w};
    #pragma unroll
    for (int e = 0; e < 4; ++e) {
      a0 += vv[e] * Wg[(c + e) * 3 + 0];
      a1 += vv[e] * Wg[(c + e) * 3 + 1];
      a2 += vv[e] * Wg[(c + e) * 3 + 2];
    }
  }
  #pragma unroll
  for (int off = 32; off; off >>= 1) {
    a0 += __shfl_xor(a0, off);
    a1 += __shfl_xor(a1, off);
    a2 += __shfl_xor(a2, off);
  }
  __shared__ float red[3][4];
  const int w = tid >> 6, lane = tid & 63;
  if (lane == 0) { red[0][w] = a0; red[1][w] = a1; red[2][w] = a2; }
  __syncthreads();
  if (tid == 0) {
    float s0 = red[0][0] + red[0][1] + red[0][2] + red[0][3];
    float s1 = red[1][0] + red[1][1] + red[1][2] + red[1][3];
    float s2 = red[2][0] + red[2][1] + red[2][2] + red[2][3];
    float m = fmaxf(s0, fmaxf(s1, s2));
    float e0 = expf(s0 - m), e1 = expf(s1 - m), e2 = expf(s2 - m);
    float s = 1.f / (e0 + e1 + e2);
    gate[row * 3 + 0] = e0 * s;
    gate[row * 3 + 1] = e1 * s;
    gate[row * 3 + 2] = e2 * s;
  }
}

// ---------------- transpose (+convert) -> bf16 ----------------
template<typename TIN>
__global__ __launch_bounds__(256) void transpose_to_bf16(const TIN* __restrict__ src,
                                                         unsigned short* __restrict__ dst,
                                                         int R, int C, int ldS,
                                                         long sS, long sD) {
  __shared__ unsigned short tile[32][33];
  int z = blockIdx.z;
  src += (long)z * sS;
  dst += (long)z * sD;
  int c0 = blockIdx.x * 32, r0 = blockIdx.y * 32;
  int tx = threadIdx.x & 31, ty = threadIdx.x >> 5;  // 32 x 8
  #pragma unroll
  for (int k = 0; k < 4; k++) {
    int rr = ty + k * 8;
    tile[rr][tx] = to_bf(src[(long)(r0 + rr) * ldS + c0 + tx]);
  }
  __syncthreads();
  #pragma unroll
  for (int k = 0; k < 4; k++) {
    int cc = ty + k * 8;
    dst[(long)(c0 + cc) * R + r0 + tx] = tile[tx][cc];
  }
}

// ---------------- 128^2 GEMM (2-phase): C = A[M,K](lda) * Bt[N,K](ldb)^T ----------------
enum { EPI_BF16 = 0, EPI_MASK_BF16 = 1, EPI_BLEND = 2, EPI_SCALE_F32 = 3, EPI_BLEND_F = 4 };
// TRI: 0 none, 1 scores (triangle + decay-band tile skip), 2 retrieved (kstart=m0, kend=band)

template<int EPI, int TRI, int SWZ>
__global__ __launch_bounds__(256) void gemm_bt(
    const unsigned short* __restrict__ A, const unsigned short* __restrict__ Bt,
    void* __restrict__ Cv, void* __restrict__ Cv2, int M, int N, int K,
    int lda, int ldb, int ldc,
    long sA, long sB, long sC,
    const float* __restrict__ decay_logits, int scale_idx,
    const float* __restrict__ gate, const float* __restrict__ out_scale,
    int blend_init) {
  int m0, n0;
  if (SWZ) {
    int nwg = gridDim.x * gridDim.y;
    int orig = blockIdx.y * gridDim.x + blockIdx.x;
    int wg = xcd_swizzle(orig, nwg);
    m0 = (wg / gridDim.x) * 128;
    n0 = (wg % gridDim.x) * 128;
  } else {
    m0 = blockIdx.y * 128;
    n0 = blockIdx.x * 128;
  }
  const int z = blockIdx.z;
  if (TRI == 1 && (n0 + 127) <= m0) return;

  // decay band: terms with w < 2^-24 are numerically irrelevant.
  // Band lives along N for scores (TRI=1), along K for retrieved (TRI=2).
  float l2d_s = 0.f;
  int bandt = K;
  if (TRI == 1 || TRI == 2) {
    const int lim = (TRI == 1) ? N : K;
    float dlv = decay_logits[scale_idx];
    float decay = 1.f / (1.f + expf(-dlv));
    l2d_s = log2f(decay);
    float bf_ = 24.0f / fmaxf(-l2d_s, 1e-9f) + 129.0f;
    bandt = (bf_ >= (float)lim) ? lim : ((int)ceilf(bf_ / 128.0f)) * 128;
    if (bandt > lim) bandt = lim;
  }
  if (TRI == 1 && n0 >= m0 + bandt) return;

  A += (long)z * sA;
  Bt += (long)z * sB;

  __shared__ unsigned short a_t[128][32];
  __shared__ unsigned short b_t[128][32];

  const int tid = threadIdx.x;
  const int wave = tid >> 6, lane = tid & 63;
  const int wm = wave >> 1, wn = wave & 1;
  const int lrow = lane & 15;
  const int g = lane >> 4;

  f32x4 acc[4][4];
  #pragma unroll
  for (int i = 0; i < 4; i++)
    #pragma unroll
    for (int j = 0; j < 4; j++) acc[i][j] = (f32x4){0.f, 0.f, 0.f, 0.f};

  const int srw = lane >> 2;
  const int scol = (lane & 3) * 8;
  const unsigned short* Ag = A + (long)(m0 + wave * 16 + srw) * lda + scol;
  const unsigned short* Bg = Bt + (long)(n0 + wave * 16 + srw) * ldb + scol;
  unsigned short* aDst = &a_t[0][0] + wave * 512;
  unsigned short* bDst = &b_t[0][0] + wave * 512;

  const int kstart = (TRI == 2) ? m0 : 0;
  const int kend = (TRI == 2) ? min(K, m0 + bandt) : K;

  for (int k0 = kstart; k0 < kend; k0 += 32) {
    async_copy16(Ag + k0, aDst);
    async_copy16(Ag + (long)64 * lda + k0, aDst + 2048);
    async_copy16(Bg + k0, bDst);
    async_copy16(Bg + (long)64 * ldb + k0, bDst + 2048);
    __syncthreads();
    short8 af[4], bf[4];
    #pragma unroll
    for (int i = 0; i < 4; i++) af[i] = *(const short8*)&a_t[wm * 64 + i * 16 + lrow][g * 8];
    #pragma unroll
    for (int j = 0; j < 4; j++) bf[j] = *(const short8*)&b_t[wn * 64 + j * 16 + lrow][g * 8];
    #pragma unroll
    for (int i = 0; i < 4; i++)
      #pragma unroll
      for (int j = 0; j < 4; j++)
        acc[i][j] = __builtin_amdgcn_mfma_f32_16x16x32_bf16(af[i], bf[j], acc[i][j], 0, 0, 0);
    __syncthreads();
  }

  const int orow = m0 + wm * 64;
  const int ocol = n0 + wn * 64;

  if (EPI == EPI_BF16) {
    unsigned short* C = (unsigned short*)Cv + (long)z * sC;
    #pragma unroll
    for (int i = 0; i < 4; i++)
      #pragma unroll
      for (int j = 0; j < 4; j++)
        #pragma unroll
        for (int e = 0; e < 4; e++) {
          int r = orow + i * 16 + g * 4 + e;
          int c = ocol + j * 16 + lrow;
          C[(long)r * ldc + c] = f2bf(acc[i][j][e]);
        }
  } else if (EPI == EPI_MASK_BF16) {
    unsigned short* C = (unsigned short*)Cv + (long)z * sC;
    #pragma unroll
    for (int i = 0; i < 4; i++)
      #pragma unroll
      for (int j = 0; j < 4; j++)
        #pragma unroll
        for (int e = 0; e < 4; e++) {
          int t = orow + i * 16 + g * 4 + e;
          int s = ocol + j * 16 + lrow;
          float w = (s > t) ? exp2f(l2d_s * (float)(s - t - 1)) : 0.f;
          C[(long)t * ldc + s] = f2bf(acc[i][j][e] * w);
        }
  } else if (EPI == EPI_BLEND || EPI == EPI_BLEND_F) {
    float* C = (float*)Cv + (long)z * sC;
    unsigned short* C2 = (unsigned short*)Cv2 + (long)z * sC;
    #pragma unroll
    for (int i = 0; i < 4; i++) {
      #pragma unroll
      for (int e = 0; e < 4; e++) {
        int t = orow + i * 16 + g * 4 + e;
        float gv = gate[((long)z * M + t) * 3 + scale_idx];
        #pragma unroll
        for (int j = 0; j < 4; j++) {
          int d = ocol + j * 16 + lrow;
          long idx = (long)t * ldc + d;
          float val = gv * acc[i][j][e];
          if (EPI == EPI_BLEND) {
            C[idx] = blend_init ? val : (C[idx] + val);
          } else {
            C2[idx] = f2bf(C[idx] + val);  // final scale: accumulate + cast to bf16
          }
        }
      }
    }
  } else {
    float sc = *out_scale;
    float* C = (float*)Cv + (long)z * sC;
    #pragma unroll
    for (int i = 0; i < 4; i++)
      #pragma unroll
      for (int j = 0; j < 4; j++)
        #pragma unroll
        for (int e = 0; e < 4; e++) {
          int r = orow + i * 16 + g * 4 + e;
          int c = ocol + j * 16 + lrow;
          C[(long)r * ldc + c] = acc[i][j][e] * sc;
        }
  }
}

// ---------------- 256^2 8-wave fine-phase counted-vmcnt GEMM ----------------
// BM=BN=256, BK=64, 512 threads (2x4 waves), per-wave C = 128x64.
// Per K-tile: 4 phases {ds_read quadrant frags | stage 2 of next tile's 8
// loads -> barrier -> lgkm(0) -> setprio(1) 16xMFMA setprio(0) -> barrier},
// vmcnt(2) counted once per tile (phase 0), never drain-0 in main loop.

DEV void stage_pair(const unsigned short* P, int ldp, int base, int k0,
                    int w, int rl, int colel, unsigned short* dst, int s0) {
  async_copy16(P + (long)(base + s0 * 64 + rl) * ldp + k0 + colel,
               dst + ((s0 * 8192 + w * 1024) >> 1));
  async_copy16(P + (long)(base + (s0 + 1) * 64 + rl) * ldp + k0 + colel,
               dst + (((s0 + 1) * 8192 + w * 1024) >> 1));
}

DEV void ds_read_A4(const unsigned short* As, int wm, int lr, int cb, int h,
                    short8 (&af)[4]) {
  #pragma unroll
  for (int ii = 0; ii < 4; ++ii)
    af[ii] = *(const short8*)((const char*)As + (wm * 128 + (h * 4 + ii) * 16 + lr) * 128 + cb);
}

DEV void ds_read_B4(const unsigned short* Bs, int wn, int lr, int cb, short8 (&bf)[4]) {
  #pragma unroll
  for (int jj = 0; jj < 4; ++jj)
    bf[jj] = *(const short8*)((const char*)Bs + (wn * 64 + jj * 16 + lr) * 128 + cb);
}

DEV void mfma16(const short8 (&af)[4], const short8 (&bf)[4], int h, f32x4 (&acc)[8][4]) {
  __builtin_amdgcn_s_setprio(1);
  #pragma unroll
  for (int ii = 0; ii < 4; ++ii)
    #pragma unroll
    for (int jj = 0; jj < 4; ++jj)
      acc[h * 4 + ii][jj] =
          __builtin_amdgcn_mfma_f32_16x16x32_bf16(af[ii], bf[jj], acc[h * 4 + ii][jj], 0, 0, 0);
  __builtin_amdgcn_s_setprio(0);
}

template<bool STAGE>
DEV void tile_phases(const unsigned short* As, const unsigned short* Bs,
                     const unsigned short* A, const unsigned short* Bt,
                     int lda, int ldb, int m0, int n0, int k1,
                     int w, int rl, int colel, unsigned short* bufn,
                     int wm, int wn, int lr, int g, f32x4 (&acc)[8][4]) {
  short8 af[4], bf[4];
  const int cb0 = (g * 16) ^ ((lr & 7) << 4);
  const int cb1 = (64 + g * 16) ^ ((lr & 7) << 4);

  // ---- phase 0 (ks=0, A-half 0; also B(ks0)) ----
  if (STAGE) {
    stage_pair(A, lda, m0, k1, w, rl, colel, bufn, 0);
    asm volatile("s_waitcnt vmcnt(2)" ::: "memory");  // this tile resident; 2 in flight
  } else {
    asm volatile("s_waitcnt vmcnt(0)" ::: "memory");
  }
  __builtin_amdgcn_s_barrier();
  __builtin_amdgcn_sched_barrier(0);
  ds_read_A4(As, wm, lr, cb0, 0, af);
  ds_read_B4(Bs, wn, lr, cb0, bf);
  asm volatile("s_waitcnt lgkmcnt(0)" ::: "memory");
  __builtin_amdgcn_sched_barrier(0);
  mfma16(af, bf, 0, acc);
  __builtin_amdgcn_s_barrier();

  // ---- phase 1 (ks=0, A-half 1; reuse bf) ----
  ds_read_A4(As, wm, lr, cb0, 1, af);
  if (STAGE) stage_pair(A, lda, m0, k1, w, rl, colel, bufn, 2);
  __builtin_amdgcn_s_barrier();
  asm volatile("s_waitcnt lgkmcnt(0)" ::: "memory");
  __builtin_amdgcn_sched_barrier(0);
  mfma16(af, bf, 1, acc);
  __builtin_amdgcn_s_barrier();

  // ---- phase 2 (ks=1, A-half 0; B(ks1)) ----
  ds_read_A4(As, wm, lr, cb1, 0, af);
  ds_read_B4(Bs, wn, lr, cb1, bf);
  if (STAGE) stage_pair(Bt, ldb, n0, k1, w, rl, colel, bufn + 16384, 0);
  __builtin_amdgcn_s_barrier();
  asm volatile("s_waitcnt lgkmcnt(0)" ::: "memory");
  __builtin_amdgcn_sched_barrier(0);
  mfma16(af, bf, 0, acc);
  __builtin_amdgcn_s_barrier();

  // ---- phase 3 (ks=1, A-half 1; reuse bf) ----
  ds_read_A4(As, wm, lr, cb1, 1, af);
  if (STAGE) stage_pair(Bt, ldb, n0, k1, w, rl, colel, bufn + 16384, 2);
  __builtin_amdgcn_s_barrier();
  asm volatile("s_waitcnt lgkmcnt(0)" ::: "memory");
  __builtin_amdgcn_sched_barrier(0);
  mfma16(af, bf, 1, acc);
  __builtin_amdgcn_s_barrier();
}

DEV void stage_tile256(const unsigned short* A, const unsigned short* Bt,
                       int lda, int ldb, int m0, int n0, int k0,
                       int w, int rl, int colel, unsigned short* buf) {
  #pragma unroll
  for (int s = 0; s < 4; ++s)
    async_copy16(A + (long)(m0 + s * 64 + rl) * lda + k0 + colel,
                 buf + ((s * 8192 + w * 1024) >> 1));
  #pragma unroll
  for (int s = 0; s < 4; ++s)
    async_copy16(Bt + (long)(n0 + s * 64 + rl) * ldb + k0 + colel,
                 buf + 16384 + ((s * 8192 + w * 1024) >> 1));
}

template<int EPI, int SWZ>
__global__ __launch_bounds__(512) void gemm256(
    const unsigned short* __restrict__ A, const unsigned short* __restrict__ Bt,
    void* __restrict__ Cv, int M, int N, int K, int lda, int ldb, int ldc,
    const float* __restrict__ out_scale) {
  __shared__ __align__(16) unsigned short lds[65536];  // 2 bufs x (As 32K + Bs 32K)
  int m0, n0;
  {
    int gx = gridDim.x;
    int orig = blockIdx.y * gx + blockIdx.x;
    int wg = SWZ ? xcd_swizzle(orig, gx * gridDim.y) : orig;
    m0 = (wg / gx) * 256;
    n0 = (wg % gx) * 256;
  }
  const int tid = threadIdx.x;
  const int w = tid >> 6, lane = tid & 63;
  const int wm = w >> 2, wn = w & 3;
  const int lr = lane & 15, g = lane >> 4;
  const int rl = w * 8 + (lane >> 3);
  const int colel = ((lane & 7) ^ (lane >> 3)) << 3;  // pre-swizzled global col (elements)

  f32x4 acc[8][4];
  #pragma unroll
  for (int i = 0; i < 8; ++i)
    #pragma unroll
    for (int j = 0; j < 4; ++j) acc[i][j] = (f32x4){0.f, 0.f, 0.f, 0.f};

  const int nkt = K >> 6;
  stage_tile256(A, Bt, lda, ldb, m0, n0, 0, w, rl, colel, lds);  // tile 0 -> buf0
  int cur = 0;
  for (int t = 0; t < nkt - 1; ++t) {
    const unsigned short* As = lds + (cur << 15);
    unsigned short* bufn = lds + ((cur ^ 1) << 15);
    tile_phases<true>(As, As + 16384, A, Bt, lda, ldb, m0, n0, (t + 1) << 6,
                      w, rl, colel, bufn, wm, wn, lr, g, acc);
    cur ^= 1;
  }
  {
    const unsigned short* As = lds + (cur << 15);
    tile_phases<false>(As, As + 16384, A, Bt, lda, ldb, m0, n0, 0,
                       w, rl, colel, nullptr, wm, wn, lr, g, acc);
  }

  const int orow = m0 + wm * 128;
  const int ocol = n0 + wn * 64;
  if (EPI == EPI_BF16) {
    unsigned short* C = (unsigned short*)Cv;
    #pragma unroll
    for (int i = 0; i < 8; ++i)
      #pragma unroll
      for (int j = 0; j < 4; ++j)
        #pragma unroll
        for (int e = 0; e < 4; ++e)
          C[(long)(orow + i * 16 + g * 4 + e) * ldc + ocol + j * 16 + lr] = f2bf(acc[i][j][e]);
  } else {  // EPI_SCALE_F32
    float sc = *out_scale;
    float* C = (float*)Cv;
    #pragma unroll
    for (int i = 0; i < 8; ++i)
      #pragma unroll
      for (int j = 0; j < 4; ++j)
        #pragma unroll
        for (int e = 0; e < 4; ++e)
          C[(long)(orow + i * 16 + g * 4 + e) * ldc + ocol + j * 16 + lr] = acc[i][j][e] * sc;
  }
}

extern "C" void kernel_launch(void* const* d_in, const int* in_sizes, int n_in,
                              void* d_out, int out_size, void* d_ws, size_t ws_size,
                              hipStream_t stream) {
  const int B = 4, T = 2048, V = 2048, D = 512;
  const int M = B * T;       // 8192
  const int NP = 7 * D;      // 3584 fused projection width

  const float* x   = (const float*)d_in[0];
  const float* Wq  = (const float*)d_in[1];
  const float* Wk  = (const float*)d_in[2];
  const float* Wv  = (const float*)d_in[3];
  const float* Wo  = (const float*)d_in[4];
  const float* Wg  = (const float*)d_in[5];
  const float* dl  = (const float*)d_in[6];
  const float* osc = (const float*)d_in[7];

  char* p = (char*)d_ws;
  auto carve = [&](size_t bytes) -> void* {
    void* r = (void*)p;
    p += (bytes + 255) & ~(size_t)255;
    return r;
  };
  unsigned short* xb   = (unsigned short*)carve((size_t)M * V * 2);
  unsigned short* wall = (unsigned short*)carve((size_t)NP * V * 2);
  unsigned short* wqT  = wall;
  unsigned short* wkT  = wall + (size_t)D * V;
  unsigned short* wvT  = wall + (size_t)4 * D * V;
  unsigned short* woT  = (unsigned short*)carve((size_t)V * D * 2);
  unsigned short* qkv  = (unsigned short*)carve((size_t)M * NP * 2);
  unsigned short* vT   = (unsigned short*)carve((size_t)B * D * T * 2);
  unsigned short* sb   = (unsigned short*)carve((size_t)B * T * T * 2);
  float*          gate = (float*)carve((size_t)M * 3 * 4);
  float*          blnd = (float*)carve((size_t)M * D * 4);
  unsigned short* blb  = (unsigned short*)carve((size_t)M * D * 2);

  // 1. fused x->bf16 + gate softmax
  convert_gate<<<dim3(M), dim3(256), 0, stream>>>(x, Wg, xb, gate);
  // 2. weight transposes (+bf16)
  transpose_to_bf16<float><<<dim3(D / 32, V / 32, 1), dim3(256), 0, stream>>>(Wq, wqT, V, D, D, 0, 0);
  transpose_to_bf16<float><<<dim3(D / 32, V / 32, 3), dim3(256), 0, stream>>>(Wk, wkT, V, D, D, (long)V * D, (long)D * V);
  transpose_to_bf16<float><<<dim3(D / 32, V / 32, 3), dim3(256), 0, stream>>>(Wv, wvT, V, D, D, (long)V * D, (long)D * V);
  transpose_to_bf16<float><<<dim3(V / 32, D / 32, 1), dim3(256), 0, stream>>>(Wo, woT, D, V, V, 0, 0);
  // 3. fused projections: qkv[M, 3584] = xb @ wall^T
  gemm256<EPI_BF16, 1><<<dim3(NP / 256, M / 256, 1), dim3(512), 0, stream>>>(
      xb, wall, qkv, M, NP, V, V, V, NP, nullptr);
  // 4. per-scale
  for (int i = 0; i < 3; i++) {
    transpose_to_bf16<unsigned short><<<dim3(D / 32, T / 32, B), dim3(256), 0, stream>>>(
        qkv + 2048 + i * 512, vT, T, D, NP, (long)T * NP, (long)D * T);
    gemm_bt<EPI_MASK_BF16, 1, 0><<<dim3(T / 128, T / 128, B), dim3(256), 0, stream>>>(
        qkv, qkv + (1 + i) * 512, sb, nullptr, T, T, D, NP, NP, T,
        (long)T * NP, (long)T * NP, (long)T * T, dl, i, nullptr, nullptr, 0);
    if (i < 2)
      gemm_bt<EPI_BLEND, 2, 0><<<dim3(D / 128, T / 128, B), dim3(256), 0, stream>>>(
          sb, vT, blnd, nullptr, T, D, T, T, T, D,
          (long)T * T, (long)D * T, (long)T * D, dl, i, gate, nullptr, (i == 0) ? 1 : 0);
    else
      gemm_bt<EPI_BLEND_F, 2, 0><<<dim3(D / 128, T / 128, B), dim3(256), 0, stream>>>(
          sb, vT, blnd, blb, T, D, T, T, T, D,
          (long)T * T, (long)D * T, (long)T * D, dl, i, gate, nullptr, 0);
  }
  // 5. out = (blended @ Wo) * out_scale  (fp32 out)
  gemm256<EPI_SCALE_F32, 1><<<dim3(V / 256, M / 256, 1), dim3(512), 0, stream>>>(
      blb, woT, d_out, M, V, D, D, D, V, osc);
}